// Round 1
// baseline (1236.662 us; speedup 1.0000x reference)
//
#include <hip/hip_runtime.h>
#include <stdint.h>

#define S_DIM 16384
#define T_DIM 8192
#define B_DIM 16
#define NH    16
#define CAP   272          // candidate buffer entries per key per wave
#define WPB   4            // waves per block

__device__ __forceinline__ uint64_t shfl64(uint64_t v, int src) {
    return (uint64_t)__shfl((long long)v, src, 64);
}
__device__ __forceinline__ uint64_t shflxor64(uint64_t v, int m) {
    return (uint64_t)__shfl_xor((long long)v, m, 64);
}
__device__ __forceinline__ uint64_t wave_min64(uint64_t v) {
#pragma unroll
    for (int m = 1; m < 64; m <<= 1) {
        uint64_t o = shflxor64(v, m);
        v = (o < v) ? o : v;
    }
    return v;
}

// Append candidate (bits,idx) to per-wave LDS buffer if bits < tau.
// ballot + mbcnt slotting, no atomics. cnt is wave-uniform.
__device__ __forceinline__ void push_cand(uint32_t bits, uint32_t idx, uint32_t tau,
                                          uint64_t* buf, int& cnt) {
    bool p = bits < tau;
    uint64_t mask = __ballot(p);
    if (p) {
        uint32_t below = __builtin_amdgcn_mbcnt_hi((uint32_t)(mask >> 32),
                          __builtin_amdgcn_mbcnt_lo((uint32_t)mask, 0u));
        buf[cnt + (int)below] = ((uint64_t)bits << 32) | (uint64_t)idx;
    }
    cnt += (int)__popcll(mask);
}

// Exact top-16 of buf[0..cnt) by (value_bits, index) lexicographic (uint64 order).
// Result: lanes 0..15 hold ranks 0..15 in res; buffer reset to those 16; tau = rank-15 bits.
// Must be called with the full wave converged; cnt <= CAP so <=5 entries/lane.
__device__ __forceinline__ void compact(uint64_t* buf, int& cnt, uint32_t& tau,
                                        uint64_t& res, int lane) {
    uint64_t loc[5];
#pragma unroll
    for (int q = 0; q < 5; ++q) loc[q] = ~0ull;
    for (int i = lane; i < cnt; i += 64) {
        uint64_t k = buf[i];
        // sorted insert (ascending), constant indices only (no spills)
#pragma unroll
        for (int q = 4; q > 0; --q)
            loc[q] = (k < loc[q-1]) ? loc[q-1] : ((k < loc[q]) ? k : loc[q]);
        loc[0] = (k < loc[0]) ? k : loc[0];
    }
    uint64_t r = ~0ull;
    for (int rr = 0; rr < 16; ++rr) {
        uint64_t m = wave_min64(loc[0]);
        if (lane == rr) r = m;
        if (loc[0] == m) {   // unique winner (keys carry unique indices)
            loc[0] = loc[1]; loc[1] = loc[2]; loc[2] = loc[3]; loc[3] = loc[4];
            loc[4] = ~0ull;
        }
    }
    res = r;
    if (lane < 16) buf[lane] = r;
    cnt = 16;
    tau = (uint32_t)(shfl64(r, 15) >> 32);
}

__global__ __launch_bounds__(WPB * 64)
void nn_topk_kernel(const float* __restrict__ x,
                    const float* __restrict__ dlon,
                    const float* __restrict__ dlat,
                    float* __restrict__ out_x,    // [B,T,NH] f32
                    float* __restrict__ out_id,   // [T,NH] as f32
                    float* __restrict__ out_il,   // [T,NH] as f32
                    float* __restrict__ out_it)   // [T,NH] as f32
{
    __shared__ uint64_t lds[WPB][3][CAP];
    const int lane = threadIdx.x & 63;
    const int wv   = threadIdx.x >> 6;
    const int t    = blockIdx.x * WPB + wv;
    if (t >= T_DIM) return;

    uint64_t* bd = lds[wv][0];
    uint64_t* bl = lds[wv][1];
    uint64_t* bt = lds[wv][2];
    uint32_t tau_d = 0xFFFFFFFFu, tau_l = 0xFFFFFFFFu, tau_t = 0xFFFFFFFFu;
    int cd = 0, cl = 0, ct = 0;
    uint64_t rd = ~0ull, rl = ~0ull, rt = ~0ull;

    const float2* plon = (const float2*)(dlon + (size_t)t * S_DIM);
    const float2* plat = (const float2*)(dlat + (size_t)t * S_DIM);

    for (int it = 0; it < S_DIM / 128; ++it) {
        float2 lo = plon[it * 64 + lane];
        float2 la = plat[it * 64 + lane];
        uint32_t i0 = (uint32_t)(it * 128 + lane * 2);
        {
            // exact numpy f32 semantics: rn mul, rn add, rn sqrt
            float dv = __fsqrt_rn(__fadd_rn(__fmul_rn(lo.x, lo.x), __fmul_rn(la.x, la.x)));
            push_cand(__float_as_uint(dv),        i0, tau_d, bd, cd);
            push_cand(__float_as_uint(fabsf(lo.x)), i0, tau_l, bl, cl);
            push_cand(__float_as_uint(fabsf(la.x)), i0, tau_t, bt, ct);
        }
        {
            float dv = __fsqrt_rn(__fadd_rn(__fmul_rn(lo.y, lo.y), __fmul_rn(la.y, la.y)));
            push_cand(__float_as_uint(dv),        i0 + 1, tau_d, bd, cd);
            push_cand(__float_as_uint(fabsf(lo.y)), i0 + 1, tau_l, bl, cl);
            push_cand(__float_as_uint(fabsf(la.y)), i0 + 1, tau_t, bt, ct);
        }
        // <=128 pushes/iter per key; compact before overflow is possible
        if (cd > CAP - 128) compact(bd, cd, tau_d, rd, lane);
        if (cl > CAP - 128) compact(bl, cl, tau_l, rl, lane);
        if (ct > CAP - 128) compact(bt, ct, tau_t, rt, lane);
    }
    compact(bd, cd, tau_d, rd, lane);
    compact(bl, cl, tau_l, rl, lane);
    compact(bt, ct, tau_t, rt, lane);

    // indices outputs (harness reads whole d_out as float32)
    if (lane < 16) {
        size_t o = (size_t)t * NH + lane;
        out_id[o] = (float)(uint32_t)(rd & 0xFFFFFFFFull);
        out_il[o] = (float)(uint32_t)(rl & 0xFFFFFFFFull);
        out_it[o] = (float)(uint32_t)(rt & 0xFFFFFFFFull);
    }

    // gather x_nearest: lane -> (b = lane>>2, j-group = lane&3), float4 store
    int b  = lane >> 2;
    int jg = lane & 3;
    uint32_t j0 = (uint32_t)(shfl64(rd, jg * 4 + 0) & 0xFFFFFFFFull);
    uint32_t j1 = (uint32_t)(shfl64(rd, jg * 4 + 1) & 0xFFFFFFFFull);
    uint32_t j2 = (uint32_t)(shfl64(rd, jg * 4 + 2) & 0xFFFFFFFFull);
    uint32_t j3 = (uint32_t)(shfl64(rd, jg * 4 + 3) & 0xFFFFFFFFull);
    const float* xb = x + (size_t)b * S_DIM;
    float4 v;
    v.x = xb[j0]; v.y = xb[j1]; v.z = xb[j2]; v.w = xb[j3];
    *(float4*)(out_x + ((size_t)b * T_DIM + t) * NH + jg * 4) = v;
}

extern "C" void kernel_launch(void* const* d_in, const int* in_sizes, int n_in,
                              void* d_out, int out_size, void* d_ws, size_t ws_size,
                              hipStream_t stream) {
    const float* x    = (const float*)d_in[0];
    const float* dlon = (const float*)d_in[1];
    const float* dlat = (const float*)d_in[2];
    // d_in[3] = nh (16), hard-coded

    float* out_x  = (float*)d_out;                          // 16*8192*16
    float* out_id = out_x  + (size_t)B_DIM * T_DIM * NH;    // 8192*16
    float* out_il = out_id + (size_t)T_DIM * NH;
    float* out_it = out_il + (size_t)T_DIM * NH;

    dim3 grid(T_DIM / WPB);
    dim3 block(WPB * 64);
    nn_topk_kernel<<<grid, block, 0, stream>>>(x, dlon, dlat, out_x, out_id, out_il, out_it);
}